// Round 6
// baseline (688.003 us; speedup 1.0000x reference)
//
#include <hip/hip_runtime.h>
#include <math.h>

#define BM 128
#define BN 128
#define BK 64

typedef _Float16 f16x8 __attribute__((ext_vector_type(8)));
typedef __attribute__((ext_vector_type(4))) float f32x4;

typedef const __attribute__((address_space(1))) void* gas_ptr;
typedef __attribute__((address_space(3))) void* las_ptr;

enum { OP_NONE = 0, OP_BIAS_GELU = 1, OP_BIAS = 2, OP_SCALE_MASK = 3 };

__device__ __forceinline__ unsigned short f2h(float f) {
    _Float16 h = (_Float16)f;  // RTNE
    unsigned short u;
    __builtin_memcpy(&u, &h, 2);
    return u;
}
__device__ __forceinline__ float h2f(unsigned short u) {
    _Float16 h;
    __builtin_memcpy(&h, &u, 2);
    return (float)h;
}

// tanh-form GELU in sigmoid shape: x * sigma(2*0.7978845608*(x+0.044715x^3)).
// ~7 VALU instrs (v_exp_f32 + v_rcp_f32) vs ~50 for libm erff. Max approx
// error vs erf-GELU ~3e-3 in h; after W2 (gain ~ sqrt(1024)*0.02) ~6e-4 —
// invisible vs fp16 rounding at our 0.1 absmax budget (R5: 0.031).
__device__ __forceinline__ float fast_gelu(float x) {
    float x2 = x * x;
    float p  = x * (-1.5957691216f - 0.0713548164f * x2);  // = -2u
    float t  = __expf(p);                                  // e^{-2u}
    return x * __builtin_amdgcn_rcpf(1.0f + t);            // x * sigma(2u)
}

// C = A @ B, B given transposed (BT is [N][K] row-major). A [M][K], C [M][N].
// fp16 in/out, fp32 accumulate. BK=64 XOR-swizzled global_load_lds staging
// (0 bank conflicts, R4). Grid (M-tiles, N-tiles, z) with M fastest -> blocks
// sharing an A-stripe land on one XCD (R5: FETCH 400->114 MB).
// Epilogue: per-wave LDS repack of the 64x64 quadrant, then 8x16B stores per
// lane filling exactly one 128B line (kills R5's 176-vs-100MB write amp).
template <int EPI, bool CAUSAL_K>
__global__ __launch_bounds__(256) void gemm_bt(
    const unsigned short* __restrict__ A,
    const unsigned short* __restrict__ BT,
    unsigned short* __restrict__ Cw,
    const float* __restrict__ bias0,
    const float* __restrict__ bias1,
    const float* __restrict__ bias2,
    int M, int N, int K,
    long long sA, long long sB, long long sC,
    float scale)
{
    __shared__ __align__(16) unsigned short smem[2 * BM * BK];  // 32 KiB
    unsigned short* As = smem;             // BM*BK = 8192 shorts
    unsigned short* Bs = smem + BM * BK;

    const int tid  = threadIdx.x;
    const int wave = tid >> 6;
    const int lane = tid & 63;

    const int bm = blockIdx.x * BM;   // M fastest -> XCD-local A reuse
    const int bn = blockIdx.y * BN;
    const int z  = blockIdx.z;

    // scores tiles fully above the diagonal are never read downstream
    if (EPI == OP_SCALE_MASK && bn >= bm + BM) return;

    const unsigned short* Ab = A  + (long long)z * sA;
    const unsigned short* Bb = BT + (long long)z * sB;
    unsigned short*       Cb = Cw + (long long)z * sC;
    const float* bias = nullptr;
    if (EPI == OP_BIAS || EPI == OP_BIAS_GELU)
        bias = (z == 0) ? bias0 : (z == 1) ? bias1 : bias2;

    const int wm = (wave >> 1) * 64;  // wave's 64x64 quadrant
    const int wn = (wave & 1) * 64;

    f32x4 acc[4][4];
    #pragma unroll
    for (int i = 0; i < 4; i++)
        #pragma unroll
        for (int j = 0; j < 4; j++)
            acc[i][j] = (f32x4){0.f, 0.f, 0.f, 0.f};

    int Keff = K;
    if (CAUSAL_K) {
        int kl = bm + BM;
        Keff = kl < K ? kl : K;
    }

    const int srow = lane >> 3;                          // row within 8-row slab
    const int gchw = ((lane & 7) ^ (srow & 7)) * 8;      // swizzled chunk, halfwords
    const int fr   = lane & 15;
    const int quad = lane >> 4;

    // per-lane global staging pointers; advance by BK per iter
    const unsigned short* pA = Ab + (long long)(bm + wave * 32 + srow) * K + gchw;
    const unsigned short* pB = Bb + (long long)(bn + wave * 32 + srow) * K + gchw;
    const long long rstep = 8ll * K;  // 8 rows between the 4 slabs of a wave

    for (int k0 = 0; k0 < Keff; k0 += BK) {
        #pragma unroll
        for (int s = 0; s < 4; ++s) {
            const int t = wave * 4 + s;
            __builtin_amdgcn_global_load_lds((gas_ptr)(const void*)(pA + s * rstep),
                                             (las_ptr)(void*)&As[t * 512 + lane * 8],
                                             16, 0, 0);
            __builtin_amdgcn_global_load_lds((gas_ptr)(const void*)(pB + s * rstep),
                                             (las_ptr)(void*)&Bs[t * 512 + lane * 8],
                                             16, 0, 0);
        }
        pA += BK;
        pB += BK;
        __syncthreads();  // drains vmcnt -> staged data visible

        #pragma unroll
        for (int kk = 0; kk < 2; ++kk) {
            f16x8 fa[4], fb[4];
            #pragma unroll
            for (int i = 0; i < 4; i++) {
                const int row  = wm + i * 16 + fr;
                const int slot = row * 8 + ((kk * 4 + quad) ^ (fr & 7));
                fa[i] = *(const f16x8*)&As[slot * 8];
            }
            #pragma unroll
            for (int j = 0; j < 4; j++) {
                const int row  = wn + j * 16 + fr;
                const int slot = row * 8 + ((kk * 4 + quad) ^ (fr & 7));
                fb[j] = *(const f16x8*)&Bs[slot * 8];
            }
            #pragma unroll
            for (int i = 0; i < 4; i++)
                #pragma unroll
                for (int j = 0; j < 4; j++)
                    acc[i][j] = __builtin_amdgcn_mfma_f32_16x16x32_f16(
                        fa[i], fb[j], acc[i][j], 0, 0, 0);
        }
        __syncthreads();  // protect LDS before next stage overwrites
    }
    // after the trailing barrier all LDS reads are done -> smem reusable

    // ---- epilogue ----
    // C/D layout col=lane&15, row=(lane>>4)*4+reg [m89/m91]. Per-wave repack:
    // 64x64 f16 quadrant into own 8 KiB LDS region, row-major with XOR chunk
    // swizzle: (row lr, col lc) -> lr*64 + ((lc>>3 ^ (lr&7))<<3 | (lc&7)).
    unsigned short* qsm = smem + wave * 4096;
    #pragma unroll
    for (int j = 0; j < 4; j++) {
        const int lc  = j * 16 + fr;
        const int col = bn + wn + lc;
        float bj = 0.f;
        if (EPI == OP_BIAS || EPI == OP_BIAS_GELU) bj = bias[col];
        #pragma unroll
        for (int i = 0; i < 4; i++) {
            #pragma unroll
            for (int r = 0; r < 4; r++) {
                const int lr  = i * 16 + quad * 4 + r;
                float v = acc[i][j][r];
                if (EPI == OP_BIAS_GELU) {
                    v = fast_gelu(v + bj);
                } else if (EPI == OP_BIAS) {
                    v += bj;
                } else if (EPI == OP_SCALE_MASK) {
                    v *= scale;
                    if (col > (bm + wm + lr)) v = 0.f;
                }
                qsm[lr * 64 + ((((lc >> 3) ^ (lr & 7)) << 3) | (lc & 7))] = f2h(v);
            }
        }
    }
    // wave-local RAW through LDS (cross-lane): enforce ds completion
    __asm__ volatile("s_waitcnt lgkmcnt(0)" ::: "memory");

    // read back one row per lane, store 8x16B = one full 128B line
    {
        const int lrow = lane;
        unsigned short* cptr = Cb + (long long)(bm + wm + lrow) * N + (bn + wn);
        #pragma unroll
        for (int c = 0; c < 8; c++) {
            f16x8 val = *(const f16x8*)&qsm[lrow * 64 + ((c ^ (lrow & 7)) << 3)];
            *(f16x8*)&cptr[c * 8] = val;
        }
    }
}

// fp32 -> fp16 elementwise (n divisible by 1024)
__global__ __launch_bounds__(256) void cvt_f32_f16(
    const float4* __restrict__ in, ushort4* __restrict__ out)
{
    int i = blockIdx.x * 256 + threadIdx.x;
    float4 f = in[i];
    ushort4 o;
    o.x = f2h(f.x); o.y = f2h(f.y); o.z = f2h(f.z); o.w = f2h(f.w);
    out[i] = o;
}

// all six weight matrices: fp32 -> fp16 transposed, one dispatch (z=0..5).
__global__ __launch_bounds__(256) void wprep(
    const float* __restrict__ s0, const float* __restrict__ s1,
    const float* __restrict__ s2, const float* __restrict__ s3,
    const float* __restrict__ s4, const float* __restrict__ s5,
    unsigned short* __restrict__ W1T, unsigned short* __restrict__ W2T)
{
    const int C = 1024;
    const int z = blockIdx.z;
    const float* in = (z == 0) ? s0 : (z == 1) ? s1 : (z == 2) ? s2
                    : (z == 3) ? s3 : (z == 4) ? s4 : s5;
    unsigned short* out = (z < 3) ? (W1T + (long long)z * C * C)
                                  : (W2T + (long long)(z - 3) * C * C);
    __shared__ unsigned short tile[32][33];
    const int bx = blockIdx.x * 32;  // col base
    const int by = blockIdx.y * 32;  // row base
    const int x = threadIdx.x;
    for (int y = threadIdx.y; y < 32; y += 8)
        tile[y][x] = f2h(in[(long long)(by + y) * C + (bx + x)]);
    __syncthreads();
    for (int y = threadIdx.y; y < 32; y += 8)
        out[(long long)(bx + y) * C + (by + x)] = tile[x][y];
}

// fp16 transpose, batched via z
__global__ __launch_bounds__(256) void transpose_f16(
    const unsigned short* __restrict__ in,
    unsigned short* __restrict__ out,
    int rows, int cols,
    long long sIn, long long sOut)
{
    __shared__ unsigned short tile[32][33];
    const unsigned short* ip = in  + (long long)blockIdx.z * sIn;
    unsigned short*       op = out + (long long)blockIdx.z * sOut;
    const int bx = blockIdx.x * 32;
    const int by = blockIdx.y * 32;
    const int x = threadIdx.x;
    for (int y = threadIdx.y; y < 32; y += 8)
        tile[y][x] = ip[(long long)(by + y) * cols + (bx + x)];
    __syncthreads();
    for (int y = threadIdx.y; y < 32; y += 8)
        op[(long long)(bx + y) * rows + (by + x)] = tile[x][y];
}

// one 256-thread block per row of 1024; fp16 in, fp32 params, fp32 out
__global__ __launch_bounds__(256) void layernorm_h(
    const unsigned short* __restrict__ X,
    const float* __restrict__ W,
    const float* __restrict__ Bv,
    float* __restrict__ Y)
{
    const int row = blockIdx.x;
    const int tid = threadIdx.x;
    ushort4 u = ((const ushort4*)(X + (long long)row * 1024))[tid];
    float f0 = h2f(u.x), f1 = h2f(u.y), f2 = h2f(u.z), f3 = h2f(u.w);
    float s  = f0 + f1 + f2 + f3;
    float ss = f0 * f0 + f1 * f1 + f2 * f2 + f3 * f3;
    #pragma unroll
    for (int off = 32; off > 0; off >>= 1) {
        s  += __shfl_down(s, off);
        ss += __shfl_down(ss, off);
    }
    __shared__ float red[2][4];
    const int wv = tid >> 6;
    if ((tid & 63) == 0) { red[0][wv] = s; red[1][wv] = ss; }
    __syncthreads();
    float S  = red[0][0] + red[0][1] + red[0][2] + red[0][3];
    float SS = red[1][0] + red[1][1] + red[1][2] + red[1][3];
    float mu  = S * (1.f / 1024.f);
    float var = SS * (1.f / 1024.f) - mu * mu;
    float rs  = rsqrtf(var + 1e-5f);
    float4 w4 = ((const float4*)W)[tid];
    float4 b4 = ((const float4*)Bv)[tid];
    float4 o;
    o.x = (f0 - mu) * rs * w4.x + b4.x;
    o.y = (f1 - mu) * rs * w4.y + b4.y;
    o.z = (f2 - mu) * rs * w4.z + b4.z;
    o.w = (f3 - mu) * rs * w4.w + b4.w;
    ((float4*)(Y + (long long)row * 1024))[tid] = o;
}

extern "C" void kernel_launch(void* const* d_in, const int* in_sizes, int n_in,
                              void* d_out, int out_size, void* d_ws, size_t ws_size,
                              hipStream_t stream)
{
    const int C  = 1024;
    const int T  = 2048;
    const int NB = 8;
    const int MT = NB * T;  // 16384 rows

    const float* x = (const float*)d_in[0];
    const float* W1q = (const float*)d_in[1];
    const float* b1q = (const float*)d_in[2];
    const float* W2q = (const float*)d_in[3];
    const float* b2q = (const float*)d_in[4];
    const float* W1k = (const float*)d_in[5];
    const float* b1k = (const float*)d_in[6];
    const float* W2k = (const float*)d_in[7];
    const float* b2k = (const float*)d_in[8];
    const float* W1v = (const float*)d_in[9];
    const float* b1v = (const float*)d_in[10];
    const float* W2v = (const float*)d_in[11];
    const float* b2v = (const float*)d_in[12];
    const float* lnw = (const float*)d_in[13];
    const float* lnb = (const float*)d_in[14];

    char* wsp = (char*)d_ws;
    auto take = [&](size_t bytes) {
        char* p = wsp;
        wsp += (bytes + 255) & ~(size_t)255;
        return p;
    };

    const size_t MATE = (size_t)MT * C;  // elements per [16384][1024] matrix

    unsigned short* W1T  = (unsigned short*)take((size_t)3 * C * C * 2);
    unsigned short* W2T  = (unsigned short*)take((size_t)3 * C * C * 2);
    unsigned short* xb   = (unsigned short*)take(MATE * 2);
    unsigned short* qkv  = (unsigned short*)take(3 * MATE * 2);  // q,k,v contiguous
    unsigned short* hreg = (unsigned short*)take(3 * MATE * 2);  // h; later scb+opre
    unsigned short* qb   = qkv;
    unsigned short* kb   = qkv + MATE;
    unsigned short* vb   = qkv + 2 * MATE;
    unsigned short* vT   = xb;                               // xb dead after MLP1
    unsigned short* scb  = hreg;                             // 8*T*T = 2*MATE elems
    unsigned short* opre = hreg + (size_t)NB * T * T;        // MATE elems — exact fit

    // x: fp32 -> fp16
    cvt_f32_f16<<<dim3(MT * C / 1024, 1, 1), dim3(256, 1, 1), 0, stream>>>(
        (const float4*)x, (ushort4*)xb);

    // all weights: fp32 -> fp16 transposed, one dispatch
    wprep<<<dim3(C / 32, C / 32, 6), dim3(32, 8, 1), 0, stream>>>(
        W1q, W1k, W1v, W2q, W2k, W2v, W1T, W2T);

    dim3 blk(256, 1, 1);

    // MLP GEMM1 (z = head): h_z = GELU(x @ W1_z + b1_z)   grid (M,N,z)
    gemm_bt<OP_BIAS_GELU, false><<<dim3(MT / BM, C / BN, 3), blk, 0, stream>>>(
        xb, W1T, hreg, b1q, b1k, b1v, MT, C, C,
        0, (long long)C * C, (long long)MATE, 1.f);

    // MLP GEMM2 (z = head): {q,k,v}_z = h_z @ W2_z + b2_z
    gemm_bt<OP_BIAS, false><<<dim3(MT / BM, C / BN, 3), blk, 0, stream>>>(
        hreg, W2T, qkv, b2q, b2k, b2v, MT, C, C,
        (long long)MATE, (long long)C * C, (long long)MATE, 1.f);

    // vT[b] = v[b]^T ([C][T] per batch) for the scores@v GEMM's BT operand
    transpose_f16<<<dim3(C / 32, T / 32, NB), dim3(32, 8, 1), 0, stream>>>(
        vb, vT, T, C, (long long)T * C, (long long)T * C);

    // scores = tril(q @ k^T) / sqrt(C*T); above-diagonal tiles skipped
    float inv_scale = 1.0f / sqrtf((float)C * (float)T);
    gemm_bt<OP_SCALE_MASK, false><<<dim3(T / BM, T / BN, NB), blk, 0, stream>>>(
        qb, kb, scb, nullptr, nullptr, nullptr, T, T, C,
        (long long)T * C, (long long)T * C, (long long)T * T, inv_scale);

    // out_pre = scores @ v (K limited to bm+BM by causality)
    gemm_bt<OP_NONE, true><<<dim3(T / BM, C / BN, NB), blk, 0, stream>>>(
        scb, vT, opre, nullptr, nullptr, nullptr, T, C, T,
        (long long)T * T, (long long)T * C, (long long)T * C, 1.f);

    layernorm_h<<<dim3(MT, 1, 1), dim3(256, 1, 1), 0, stream>>>(
        opre, lnw, lnb, (float*)d_out);
}

// Round 7
// 619.272 us; speedup vs baseline: 1.1110x; 1.1110x over previous
//
#include <hip/hip_runtime.h>
#include <math.h>

#define BM 128
#define BN 128
#define BK 64

typedef _Float16 f16x8 __attribute__((ext_vector_type(8)));
typedef __attribute__((ext_vector_type(4))) float f32x4;

typedef const __attribute__((address_space(1))) void* gas_ptr;
typedef __attribute__((address_space(3))) void* las_ptr;

enum { OP_NONE = 0, OP_BIAS_GELU = 1, OP_BIAS = 2, OP_SCALE_MASK = 3 };

__device__ __forceinline__ unsigned short f2h(float f) {
    _Float16 h = (_Float16)f;  // RTNE
    unsigned short u;
    __builtin_memcpy(&u, &h, 2);
    return u;
}
__device__ __forceinline__ float h2f(unsigned short u) {
    _Float16 h;
    __builtin_memcpy(&h, &u, 2);
    return (float)h;
}

// tanh-form GELU via sigmoid: ~7 VALU instrs vs ~50 for libm erff.
// Approx error ~3e-3 in h -> ~6e-4 after W2; invisible at 0.1 budget
// (R6 confirmed: absmax stayed 0.03125 with this approximation).
__device__ __forceinline__ float fast_gelu(float x) {
    float x2 = x * x;
    float p  = x * (-1.5957691216f - 0.0713548164f * x2);  // = -2u
    float t  = __expf(p);                                  // e^{-2u}
    return x * __builtin_amdgcn_rcpf(1.0f + t);            // x * sigma(2u)
}

// C = A @ B, B given transposed (BT is [N][K] row-major). A [M][K], C [M][N].
// fp16 in/out, fp32 accumulate. BK=64 XOR-swizzled global_load_lds staging
// (0 bank conflicts, R4). Grid (M-tiles, N-tiles, z) with M fastest -> blocks
// sharing an A-stripe land on one XCD (R5: FETCH 400->114 MB).
// Epilogue: DIRECT scatter stores. (R6's LDS-repack epilogue regressed the
// short-K attention kernels by ~100 us combined -- do not reintroduce.)
template <int EPI, bool CAUSAL_K>
__global__ __launch_bounds__(256) void gemm_bt(
    const unsigned short* __restrict__ A,
    const unsigned short* __restrict__ BT,
    unsigned short* __restrict__ Cw,
    const float* __restrict__ bias0,
    const float* __restrict__ bias1,
    const float* __restrict__ bias2,
    int M, int N, int K,
    long long sA, long long sB, long long sC,
    float scale)
{
    __shared__ __align__(16) unsigned short As[BM * BK];
    __shared__ __align__(16) unsigned short Bs[BN * BK];

    const int tid  = threadIdx.x;
    const int wave = tid >> 6;
    const int lane = tid & 63;

    const int bm = blockIdx.x * BM;   // M fastest -> XCD-local A reuse
    const int bn = blockIdx.y * BN;
    const int z  = blockIdx.z;

    // scores tiles fully above the diagonal are never read downstream
    if (EPI == OP_SCALE_MASK && bn >= bm + BM) return;

    const unsigned short* Ab = A  + (long long)z * sA;
    const unsigned short* Bb = BT + (long long)z * sB;
    unsigned short*       Cb = Cw + (long long)z * sC;
    const float* bias = nullptr;
    if (EPI == OP_BIAS || EPI == OP_BIAS_GELU)
        bias = (z == 0) ? bias0 : (z == 1) ? bias1 : bias2;

    const int wm = (wave >> 1) * 64;  // wave's 64x64 quadrant
    const int wn = (wave & 1) * 64;

    f32x4 acc[4][4];
    #pragma unroll
    for (int i = 0; i < 4; i++)
        #pragma unroll
        for (int j = 0; j < 4; j++)
            acc[i][j] = (f32x4){0.f, 0.f, 0.f, 0.f};

    int Keff = K;
    if (CAUSAL_K) {
        int kl = bm + BM;
        Keff = kl < K ? kl : K;
    }

    const int srow = lane >> 3;                          // row within 8-row slab
    const int gchw = ((lane & 7) ^ (srow & 7)) * 8;      // swizzled chunk, halfwords
    const int fr   = lane & 15;
    const int quad = lane >> 4;

    // per-lane global staging pointers; advance by BK per iter
    const unsigned short* pA = Ab + (long long)(bm + wave * 32 + srow) * K + gchw;
    const unsigned short* pB = Bb + (long long)(bn + wave * 32 + srow) * K + gchw;
    const long long rstep = 8ll * K;  // 8 rows between the 4 slabs of a wave

    for (int k0 = 0; k0 < Keff; k0 += BK) {
        #pragma unroll
        for (int s = 0; s < 4; ++s) {
            const int t = wave * 4 + s;
            __builtin_amdgcn_global_load_lds((gas_ptr)(const void*)(pA + s * rstep),
                                             (las_ptr)(void*)&As[t * 512 + lane * 8],
                                             16, 0, 0);
            __builtin_amdgcn_global_load_lds((gas_ptr)(const void*)(pB + s * rstep),
                                             (las_ptr)(void*)&Bs[t * 512 + lane * 8],
                                             16, 0, 0);
        }
        pA += BK;
        pB += BK;
        __syncthreads();  // drains vmcnt -> staged data visible

        #pragma unroll
        for (int kk = 0; kk < 2; ++kk) {
            f16x8 fa[4], fb[4];
            #pragma unroll
            for (int i = 0; i < 4; i++) {
                const int row  = wm + i * 16 + fr;
                const int slot = row * 8 + ((kk * 4 + quad) ^ (fr & 7));
                fa[i] = *(const f16x8*)&As[slot * 8];
            }
            #pragma unroll
            for (int j = 0; j < 4; j++) {
                const int row  = wn + j * 16 + fr;
                const int slot = row * 8 + ((kk * 4 + quad) ^ (fr & 7));
                fb[j] = *(const f16x8*)&Bs[slot * 8];
            }
            #pragma unroll
            for (int i = 0; i < 4; i++)
                #pragma unroll
                for (int j = 0; j < 4; j++)
                    acc[i][j] = __builtin_amdgcn_mfma_f32_16x16x32_f16(
                        fa[i], fb[j], acc[i][j], 0, 0, 0);
        }
        __syncthreads();  // protect LDS before next stage overwrites
    }

    // epilogue: C/D layout col=lane&15, row=(lane>>4)*4+reg  [m89/m91]
    const int er = quad;
    const int ec = fr;
    #pragma unroll
    for (int j = 0; j < 4; j++) {
        const int col = bn + wn + j * 16 + ec;
        float bj = 0.f;
        if (EPI == OP_BIAS || EPI == OP_BIAS_GELU) bj = bias[col];
        #pragma unroll
        for (int i = 0; i < 4; i++) {
            #pragma unroll
            for (int r = 0; r < 4; r++) {
                const int row = bm + wm + i * 16 + er * 4 + r;
                float v = acc[i][j][r];
                if (EPI == OP_BIAS_GELU) {
                    v = fast_gelu(v + bj);
                } else if (EPI == OP_BIAS) {
                    v += bj;
                } else if (EPI == OP_SCALE_MASK) {
                    v *= scale;
                    if (col > row) v = 0.f;
                }
                Cb[(long long)row * N + col] = f2h(v);
            }
        }
    }
}

// fp32 -> fp16 elementwise (n divisible by 1024)
__global__ __launch_bounds__(256) void cvt_f32_f16(
    const float4* __restrict__ in, ushort4* __restrict__ out)
{
    int i = blockIdx.x * 256 + threadIdx.x;
    float4 f = in[i];
    ushort4 o;
    o.x = f2h(f.x); o.y = f2h(f.y); o.z = f2h(f.z); o.w = f2h(f.w);
    out[i] = o;
}

// all six weight matrices: fp32 -> fp16 transposed, one dispatch (z=0..5).
__global__ __launch_bounds__(256) void wprep(
    const float* __restrict__ s0, const float* __restrict__ s1,
    const float* __restrict__ s2, const float* __restrict__ s3,
    const float* __restrict__ s4, const float* __restrict__ s5,
    unsigned short* __restrict__ W1T, unsigned short* __restrict__ W2T)
{
    const int C = 1024;
    const int z = blockIdx.z;
    const float* in = (z == 0) ? s0 : (z == 1) ? s1 : (z == 2) ? s2
                    : (z == 3) ? s3 : (z == 4) ? s4 : s5;
    unsigned short* out = (z < 3) ? (W1T + (long long)z * C * C)
                                  : (W2T + (long long)(z - 3) * C * C);
    __shared__ unsigned short tile[32][33];
    const int bx = blockIdx.x * 32;  // col base
    const int by = blockIdx.y * 32;  // row base
    const int x = threadIdx.x;
    for (int y = threadIdx.y; y < 32; y += 8)
        tile[y][x] = f2h(in[(long long)(by + y) * C + (bx + x)]);
    __syncthreads();
    for (int y = threadIdx.y; y < 32; y += 8)
        out[(long long)(bx + y) * C + (by + x)] = tile[x][y];
}

// fp16 transpose, batched via z
__global__ __launch_bounds__(256) void transpose_f16(
    const unsigned short* __restrict__ in,
    unsigned short* __restrict__ out,
    int rows, int cols,
    long long sIn, long long sOut)
{
    __shared__ unsigned short tile[32][33];
    const unsigned short* ip = in  + (long long)blockIdx.z * sIn;
    unsigned short*       op = out + (long long)blockIdx.z * sOut;
    const int bx = blockIdx.x * 32;
    const int by = blockIdx.y * 32;
    const int x = threadIdx.x;
    for (int y = threadIdx.y; y < 32; y += 8)
        tile[y][x] = ip[(long long)(by + y) * cols + (bx + x)];
    __syncthreads();
    for (int y = threadIdx.y; y < 32; y += 8)
        op[(long long)(bx + y) * rows + (by + x)] = tile[x][y];
}

// one 256-thread block per row of 1024; fp16 in, fp32 params, fp32 out
__global__ __launch_bounds__(256) void layernorm_h(
    const unsigned short* __restrict__ X,
    const float* __restrict__ W,
    const float* __restrict__ Bv,
    float* __restrict__ Y)
{
    const int row = blockIdx.x;
    const int tid = threadIdx.x;
    ushort4 u = ((const ushort4*)(X + (long long)row * 1024))[tid];
    float f0 = h2f(u.x), f1 = h2f(u.y), f2 = h2f(u.z), f3 = h2f(u.w);
    float s  = f0 + f1 + f2 + f3;
    float ss = f0 * f0 + f1 * f1 + f2 * f2 + f3 * f3;
    #pragma unroll
    for (int off = 32; off > 0; off >>= 1) {
        s  += __shfl_down(s, off);
        ss += __shfl_down(ss, off);
    }
    __shared__ float red[2][4];
    const int wv = tid >> 6;
    if ((tid & 63) == 0) { red[0][wv] = s; red[1][wv] = ss; }
    __syncthreads();
    float S  = red[0][0] + red[0][1] + red[0][2] + red[0][3];
    float SS = red[1][0] + red[1][1] + red[1][2] + red[1][3];
    float mu  = S * (1.f / 1024.f);
    float var = SS * (1.f / 1024.f) - mu * mu;
    float rs  = rsqrtf(var + 1e-5f);
    float4 w4 = ((const float4*)W)[tid];
    float4 b4 = ((const float4*)Bv)[tid];
    float4 o;
    o.x = (f0 - mu) * rs * w4.x + b4.x;
    o.y = (f1 - mu) * rs * w4.y + b4.y;
    o.z = (f2 - mu) * rs * w4.z + b4.z;
    o.w = (f3 - mu) * rs * w4.w + b4.w;
    ((float4*)(Y + (long long)row * 1024))[tid] = o;
}

extern "C" void kernel_launch(void* const* d_in, const int* in_sizes, int n_in,
                              void* d_out, int out_size, void* d_ws, size_t ws_size,
                              hipStream_t stream)
{
    const int C  = 1024;
    const int T  = 2048;
    const int NB = 8;
    const int MT = NB * T;  // 16384 rows

    const float* x = (const float*)d_in[0];
    const float* W1q = (const float*)d_in[1];
    const float* b1q = (const float*)d_in[2];
    const float* W2q = (const float*)d_in[3];
    const float* b2q = (const float*)d_in[4];
    const float* W1k = (const float*)d_in[5];
    const float* b1k = (const float*)d_in[6];
    const float* W2k = (const float*)d_in[7];
    const float* b2k = (const float*)d_in[8];
    const float* W1v = (const float*)d_in[9];
    const float* b1v = (const float*)d_in[10];
    const float* W2v = (const float*)d_in[11];
    const float* b2v = (const float*)d_in[12];
    const float* lnw = (const float*)d_in[13];
    const float* lnb = (const float*)d_in[14];

    char* wsp = (char*)d_ws;
    auto take = [&](size_t bytes) {
        char* p = wsp;
        wsp += (bytes + 255) & ~(size_t)255;
        return p;
    };

    const size_t MATE = (size_t)MT * C;  // elements per [16384][1024] matrix

    unsigned short* W1T  = (unsigned short*)take((size_t)3 * C * C * 2);
    unsigned short* W2T  = (unsigned short*)take((size_t)3 * C * C * 2);
    unsigned short* xb   = (unsigned short*)take(MATE * 2);
    unsigned short* qkv  = (unsigned short*)take(3 * MATE * 2);  // q,k,v contiguous
    unsigned short* hreg = (unsigned short*)take(3 * MATE * 2);  // h; later scb+opre
    unsigned short* qb   = qkv;
    unsigned short* kb   = qkv + MATE;
    unsigned short* vb   = qkv + 2 * MATE;
    unsigned short* vT   = xb;                               // xb dead after MLP1
    unsigned short* scb  = hreg;                             // 8*T*T = 2*MATE elems
    unsigned short* opre = hreg + (size_t)NB * T * T;        // MATE elems — exact fit

    // x: fp32 -> fp16
    cvt_f32_f16<<<dim3(MT * C / 1024, 1, 1), dim3(256, 1, 1), 0, stream>>>(
        (const float4*)x, (ushort4*)xb);

    // all weights: fp32 -> fp16 transposed, one dispatch
    wprep<<<dim3(C / 32, C / 32, 6), dim3(32, 8, 1), 0, stream>>>(
        W1q, W1k, W1v, W2q, W2k, W2v, W1T, W2T);

    dim3 blk(256, 1, 1);

    // MLP GEMM1 (z = head): h_z = GELU(x @ W1_z + b1_z)   grid (M,N,z)
    gemm_bt<OP_BIAS_GELU, false><<<dim3(MT / BM, C / BN, 3), blk, 0, stream>>>(
        xb, W1T, hreg, b1q, b1k, b1v, MT, C, C,
        0, (long long)C * C, (long long)MATE, 1.f);

    // MLP GEMM2 (z = head): {q,k,v}_z = h_z @ W2_z + b2_z
    gemm_bt<OP_BIAS, false><<<dim3(MT / BM, C / BN, 3), blk, 0, stream>>>(
        hreg, W2T, qkv, b2q, b2k, b2v, MT, C, C,
        (long long)MATE, (long long)C * C, (long long)MATE, 1.f);

    // vT[b] = v[b]^T ([C][T] per batch) for the scores@v GEMM's BT operand
    transpose_f16<<<dim3(C / 32, T / 32, NB), dim3(32, 8, 1), 0, stream>>>(
        vb, vT, T, C, (long long)T * C, (long long)T * C);

    // scores = tril(q @ k^T) / sqrt(C*T); above-diagonal tiles skipped
    float inv_scale = 1.0f / sqrtf((float)C * (float)T);
    gemm_bt<OP_SCALE_MASK, false><<<dim3(T / BM, T / BN, NB), blk, 0, stream>>>(
        qb, kb, scb, nullptr, nullptr, nullptr, T, T, C,
        (long long)T * C, (long long)T * C, (long long)T * T, inv_scale);

    // out_pre = scores @ v (K limited to bm+BM by causality)
    gemm_bt<OP_NONE, true><<<dim3(T / BM, C / BN, NB), blk, 0, stream>>>(
        scb, vT, opre, nullptr, nullptr, nullptr, T, C, T,
        (long long)T * T, (long long)T * C, (long long)T * C, 1.f);

    layernorm_h<<<dim3(MT, 1, 1), dim3(256, 1, 1), 0, stream>>>(
        opre, lnw, lnb, (float*)d_out);
}

// Round 8
// 592.642 us; speedup vs baseline: 1.1609x; 1.0449x over previous
//
#include <hip/hip_runtime.h>
#include <math.h>

#define BM 128
#define BN 128
#define BK 64

typedef _Float16 f16x8 __attribute__((ext_vector_type(8)));
typedef __attribute__((ext_vector_type(4))) float f32x4;

typedef const __attribute__((address_space(1))) void* gas_ptr;
typedef __attribute__((address_space(3))) void* las_ptr;

enum { OP_NONE = 0, OP_BIAS_GELU = 1, OP_BIAS = 2, OP_SCALE_MASK = 3 };

__device__ __forceinline__ unsigned short f2h(float f) {
    _Float16 h = (_Float16)f;  // RTNE
    unsigned short u;
    __builtin_memcpy(&u, &h, 2);
    return u;
}
__device__ __forceinline__ float h2f(unsigned short u) {
    _Float16 h;
    __builtin_memcpy(&h, &u, 2);
    return (float)h;
}

// tanh-form GELU via sigmoid: ~7 VALU instrs vs ~50 for libm erff.
// R6/R7 confirmed: absmax stays 0.03125 with this approximation.
__device__ __forceinline__ float fast_gelu(float x) {
    float x2 = x * x;
    float p  = x * (-1.5957691216f - 0.0713548164f * x2);  // = -2u
    float t  = __expf(p);                                  // e^{-2u}
    return x * __builtin_amdgcn_rcpf(1.0f + t);            // x * sigma(2u)
}

// C = A @ B, B given transposed (BT is [N][K] row-major). A [M][K], C [M][N].
// fp16 in/out, fp32 accumulate. BK=64 XOR-swizzled global_load_lds staging
// (0 bank conflicts, R4). M-fastest grid -> same-XCD A-stripe reuse (R5).
// Direct scatter epilogue (R6's LDS repack regressed; R7 reverted).
// TRI: packed lower-triangle grid for scores (blockIdx.x = linear tile t,
//      blockIdx.y = z; only live tiles launched — R7 had 120 dead blocks/z).
// REVM: reverse bm order (longest-K blocks first — LPT for CAUSAL_K).
template <int EPI, bool CAUSAL_K, bool TRI, bool REVM>
__global__ __launch_bounds__(256) void gemm_bt(
    const unsigned short* __restrict__ A,
    const unsigned short* __restrict__ BT,
    unsigned short* __restrict__ Cw,
    const float* __restrict__ bias0,
    const float* __restrict__ bias1,
    const float* __restrict__ bias2,
    int M, int N, int K,
    long long sA, long long sB, long long sC,
    float scale)
{
    __shared__ __align__(16) unsigned short As[BM * BK];
    __shared__ __align__(16) unsigned short Bs[BN * BK];

    const int tid  = threadIdx.x;
    const int wave = tid >> 6;
    const int lane = tid & 63;

    int bm, bn, z;
    if (TRI) {
        // unrank t -> (i, j), j <= i, t = i(i+1)/2 + j
        const int t = blockIdx.x;
        int i = (int)((sqrtf(8.0f * t + 1.0f) - 1.0f) * 0.5f);
        while ((i + 1) * (i + 2) / 2 <= t) i++;
        while (i * (i + 1) / 2 > t) i--;
        const int j = t - i * (i + 1) / 2;
        bm = i * BM;
        bn = j * BN;
        z  = blockIdx.y;
    } else {
        bm = (REVM ? (gridDim.x - 1 - blockIdx.x) : blockIdx.x) * BM;
        bn = blockIdx.y * BN;
        z  = blockIdx.z;
    }

    const unsigned short* Ab = A  + (long long)z * sA;
    const unsigned short* Bb = BT + (long long)z * sB;
    unsigned short*       Cb = Cw + (long long)z * sC;
    const float* bias = nullptr;
    if (EPI == OP_BIAS || EPI == OP_BIAS_GELU)
        bias = (z == 0) ? bias0 : (z == 1) ? bias1 : bias2;

    const int wm = (wave >> 1) * 64;  // wave's 64x64 quadrant
    const int wn = (wave & 1) * 64;

    f32x4 acc[4][4];
    #pragma unroll
    for (int i = 0; i < 4; i++)
        #pragma unroll
        for (int j = 0; j < 4; j++)
            acc[i][j] = (f32x4){0.f, 0.f, 0.f, 0.f};

    int Keff = K;
    if (CAUSAL_K) {
        int kl = bm + BM;
        Keff = kl < K ? kl : K;
    }

    const int srow = lane >> 3;                          // row within 8-row slab
    const int gchw = ((lane & 7) ^ (srow & 7)) * 8;      // swizzled chunk, halfwords
    const int fr   = lane & 15;
    const int quad = lane >> 4;

    // per-lane global staging pointers; advance by BK per iter
    const unsigned short* pA = Ab + (long long)(bm + wave * 32 + srow) * K + gchw;
    const unsigned short* pB = Bb + (long long)(bn + wave * 32 + srow) * K + gchw;
    const long long rstep = 8ll * K;  // 8 rows between the 4 slabs of a wave

    for (int k0 = 0; k0 < Keff; k0 += BK) {
        #pragma unroll
        for (int s = 0; s < 4; ++s) {
            const int t = wave * 4 + s;
            __builtin_amdgcn_global_load_lds((gas_ptr)(const void*)(pA + s * rstep),
                                             (las_ptr)(void*)&As[t * 512 + lane * 8],
                                             16, 0, 0);
            __builtin_amdgcn_global_load_lds((gas_ptr)(const void*)(pB + s * rstep),
                                             (las_ptr)(void*)&Bs[t * 512 + lane * 8],
                                             16, 0, 0);
        }
        pA += BK;
        pB += BK;
        __syncthreads();  // drains vmcnt -> staged data visible

        #pragma unroll
        for (int kk = 0; kk < 2; ++kk) {
            f16x8 fa[4], fb[4];
            #pragma unroll
            for (int i = 0; i < 4; i++) {
                const int row  = wm + i * 16 + fr;
                const int slot = row * 8 + ((kk * 4 + quad) ^ (fr & 7));
                fa[i] = *(const f16x8*)&As[slot * 8];
            }
            #pragma unroll
            for (int j = 0; j < 4; j++) {
                const int row  = wn + j * 16 + fr;
                const int slot = row * 8 + ((kk * 4 + quad) ^ (fr & 7));
                fb[j] = *(const f16x8*)&Bs[slot * 8];
            }
            #pragma unroll
            for (int i = 0; i < 4; i++)
                #pragma unroll
                for (int j = 0; j < 4; j++)
                    acc[i][j] = __builtin_amdgcn_mfma_f32_16x16x32_f16(
                        fa[i], fb[j], acc[i][j], 0, 0, 0);
        }
        __syncthreads();  // protect LDS before next stage overwrites
    }

    // epilogue: C/D layout col=lane&15, row=(lane>>4)*4+reg  [m89/m91]
    const int er = quad;
    const int ec = fr;
    #pragma unroll
    for (int j = 0; j < 4; j++) {
        const int col = bn + wn + j * 16 + ec;
        float bj = 0.f;
        if (EPI == OP_BIAS || EPI == OP_BIAS_GELU) bj = bias[col];
        #pragma unroll
        for (int i = 0; i < 4; i++) {
            #pragma unroll
            for (int r = 0; r < 4; r++) {
                const int row = bm + wm + i * 16 + er * 4 + r;
                float v = acc[i][j][r];
                if (EPI == OP_BIAS_GELU) {
                    v = fast_gelu(v + bj);
                } else if (EPI == OP_BIAS) {
                    v += bj;
                } else if (EPI == OP_SCALE_MASK) {
                    v *= scale;
                    if (col > row) v = 0.f;
                }
                Cb[(long long)row * N + col] = f2h(v);
            }
        }
    }
}

// fp32 -> fp16 elementwise (n divisible by 1024)
__global__ __launch_bounds__(256) void cvt_f32_f16(
    const float4* __restrict__ in, ushort4* __restrict__ out)
{
    int i = blockIdx.x * 256 + threadIdx.x;
    float4 f = in[i];
    ushort4 o;
    o.x = f2h(f.x); o.y = f2h(f.y); o.z = f2h(f.z); o.w = f2h(f.w);
    out[i] = o;
}

// all six weight matrices: fp32 -> fp16 transposed, one dispatch (z=0..5).
__global__ __launch_bounds__(256) void wprep(
    const float* __restrict__ s0, const float* __restrict__ s1,
    const float* __restrict__ s2, const float* __restrict__ s3,
    const float* __restrict__ s4, const float* __restrict__ s5,
    unsigned short* __restrict__ W1T, unsigned short* __restrict__ W2T)
{
    const int C = 1024;
    const int z = blockIdx.z;
    const float* in = (z == 0) ? s0 : (z == 1) ? s1 : (z == 2) ? s2
                    : (z == 3) ? s3 : (z == 4) ? s4 : s5;
    unsigned short* out = (z < 3) ? (W1T + (long long)z * C * C)
                                  : (W2T + (long long)(z - 3) * C * C);
    __shared__ unsigned short tile[32][33];
    const int bx = blockIdx.x * 32;  // col base
    const int by = blockIdx.y * 32;  // row base
    const int x = threadIdx.x;
    for (int y = threadIdx.y; y < 32; y += 8)
        tile[y][x] = f2h(in[(long long)(by + y) * C + (bx + x)]);
    __syncthreads();
    for (int y = threadIdx.y; y < 32; y += 8)
        out[(long long)(bx + y) * C + (by + x)] = tile[x][y];
}

// wide fp16 transpose: 64x64 tiles, ushort4 (8B) loads AND stores.
// grid (cols/64, rows/64, NB); out[col][row] = in[row][col].
__global__ __launch_bounds__(256) void transpose64_f16(
    const unsigned short* __restrict__ in,
    unsigned short* __restrict__ out,
    int rows, int cols,
    long long sIn, long long sOut)
{
    __shared__ unsigned short tile[64][68];  // stride 68 shorts = 136 B (8B-aligned)
    const unsigned short* ip = in  + (long long)blockIdx.z * sIn;
    unsigned short*       op = out + (long long)blockIdx.z * sOut;
    const int bx = blockIdx.x * 64;  // col base
    const int by = blockIdx.y * 64;  // row base
    const int tid = threadIdx.x;
    const int rsub = tid >> 4;        // 0..15
    const int c4   = (tid & 15) * 4;  // 0,4,..,60
    #pragma unroll
    for (int it = 0; it < 4; it++) {
        const int r = it * 16 + rsub;
        ushort4 v = *(const ushort4*)&ip[(long long)(by + r) * cols + (bx + c4)];
        tile[r][c4]     = v.x;
        tile[r][c4 + 1] = v.y;
        tile[r][c4 + 2] = v.z;
        tile[r][c4 + 3] = v.w;
    }
    __syncthreads();
    #pragma unroll
    for (int it = 0; it < 4; it++) {
        const int cc = it * 16 + rsub;  // out row = in col
        ushort4 v;
        v.x = tile[c4][cc];
        v.y = tile[c4 + 1][cc];
        v.z = tile[c4 + 2][cc];
        v.w = tile[c4 + 3][cc];
        *(ushort4*)&op[(long long)(bx + cc) * rows + (by + c4)] = v;
    }
}

// one 256-thread block per row of 1024; fp16 in, fp32 params, fp32 out
__global__ __launch_bounds__(256) void layernorm_h(
    const unsigned short* __restrict__ X,
    const float* __restrict__ W,
    const float* __restrict__ Bv,
    float* __restrict__ Y)
{
    const int row = blockIdx.x;
    const int tid = threadIdx.x;
    ushort4 u = ((const ushort4*)(X + (long long)row * 1024))[tid];
    float f0 = h2f(u.x), f1 = h2f(u.y), f2 = h2f(u.z), f3 = h2f(u.w);
    float s  = f0 + f1 + f2 + f3;
    float ss = f0 * f0 + f1 * f1 + f2 * f2 + f3 * f3;
    #pragma unroll
    for (int off = 32; off > 0; off >>= 1) {
        s  += __shfl_down(s, off);
        ss += __shfl_down(ss, off);
    }
    __shared__ float red[2][4];
    const int wv = tid >> 6;
    if ((tid & 63) == 0) { red[0][wv] = s; red[1][wv] = ss; }
    __syncthreads();
    float S  = red[0][0] + red[0][1] + red[0][2] + red[0][3];
    float SS = red[1][0] + red[1][1] + red[1][2] + red[1][3];
    float mu  = S * (1.f / 1024.f);
    float var = SS * (1.f / 1024.f) - mu * mu;
    float rs  = rsqrtf(var + 1e-5f);
    float4 w4 = ((const float4*)W)[tid];
    float4 b4 = ((const float4*)Bv)[tid];
    float4 o;
    o.x = (f0 - mu) * rs * w4.x + b4.x;
    o.y = (f1 - mu) * rs * w4.y + b4.y;
    o.z = (f2 - mu) * rs * w4.z + b4.z;
    o.w = (f3 - mu) * rs * w4.w + b4.w;
    ((float4*)(Y + (long long)row * 1024))[tid] = o;
}

extern "C" void kernel_launch(void* const* d_in, const int* in_sizes, int n_in,
                              void* d_out, int out_size, void* d_ws, size_t ws_size,
                              hipStream_t stream)
{
    const int C  = 1024;
    const int T  = 2048;
    const int NB = 8;
    const int MT = NB * T;  // 16384 rows

    const float* x = (const float*)d_in[0];
    const float* W1q = (const float*)d_in[1];
    const float* b1q = (const float*)d_in[2];
    const float* W2q = (const float*)d_in[3];
    const float* b2q = (const float*)d_in[4];
    const float* W1k = (const float*)d_in[5];
    const float* b1k = (const float*)d_in[6];
    const float* W2k = (const float*)d_in[7];
    const float* b2k = (const float*)d_in[8];
    const float* W1v = (const float*)d_in[9];
    const float* b1v = (const float*)d_in[10];
    const float* W2v = (const float*)d_in[11];
    const float* b2v = (const float*)d_in[12];
    const float* lnw = (const float*)d_in[13];
    const float* lnb = (const float*)d_in[14];

    char* wsp = (char*)d_ws;
    auto take = [&](size_t bytes) {
        char* p = wsp;
        wsp += (bytes + 255) & ~(size_t)255;
        return p;
    };

    const size_t MATE = (size_t)MT * C;  // elements per [16384][1024] matrix

    unsigned short* W1T  = (unsigned short*)take((size_t)3 * C * C * 2);
    unsigned short* W2T  = (unsigned short*)take((size_t)3 * C * C * 2);
    unsigned short* xb   = (unsigned short*)take(MATE * 2);
    unsigned short* qkv  = (unsigned short*)take(3 * MATE * 2);  // q,k,v contiguous
    unsigned short* hreg = (unsigned short*)take(3 * MATE * 2);  // h; later scb+opre
    unsigned short* qb   = qkv;
    unsigned short* kb   = qkv + MATE;
    unsigned short* vb   = qkv + 2 * MATE;
    unsigned short* vT   = xb;                               // xb dead after MLP1
    unsigned short* scb  = hreg;                             // 8*T*T = 2*MATE elems
    unsigned short* opre = hreg + (size_t)NB * T * T;        // MATE elems — exact fit

    // x: fp32 -> fp16
    cvt_f32_f16<<<dim3(MT * C / 1024, 1, 1), dim3(256, 1, 1), 0, stream>>>(
        (const float4*)x, (ushort4*)xb);

    // all weights: fp32 -> fp16 transposed, one dispatch
    wprep<<<dim3(C / 32, C / 32, 6), dim3(32, 8, 1), 0, stream>>>(
        W1q, W1k, W1v, W2q, W2k, W2v, W1T, W2T);

    dim3 blk(256, 1, 1);

    // MLP GEMM1 (z = head): h_z = GELU(x @ W1_z + b1_z)   grid (M,N,z)
    gemm_bt<OP_BIAS_GELU, false, false, false><<<dim3(MT / BM, C / BN, 3), blk, 0, stream>>>(
        xb, W1T, hreg, b1q, b1k, b1v, MT, C, C,
        0, (long long)C * C, (long long)MATE, 1.f);

    // MLP GEMM2 (z = head): {q,k,v}_z = h_z @ W2_z + b2_z
    gemm_bt<OP_BIAS, false, false, false><<<dim3(MT / BM, C / BN, 3), blk, 0, stream>>>(
        hreg, W2T, qkv, b2q, b2k, b2v, MT, C, C,
        (long long)MATE, (long long)C * C, (long long)MATE, 1.f);

    // vT[b] = v[b]^T ([C][T] per batch) for the scores@v GEMM's BT operand
    transpose64_f16<<<dim3(C / 64, T / 64, NB), blk, 0, stream>>>(
        vb, vT, T, C, (long long)T * C, (long long)T * C);

    // scores = tril(q @ k^T) / sqrt(C*T); packed lower-triangle grid:
    // 136 live tiles per z (16*17/2), 136 % 8 == 0 keeps z XCD-aligned
    float inv_scale = 1.0f / sqrtf((float)C * (float)T);
    gemm_bt<OP_SCALE_MASK, false, true, false><<<dim3(136, NB, 1), blk, 0, stream>>>(
        qb, kb, scb, nullptr, nullptr, nullptr, T, T, C,
        (long long)T * C, (long long)T * C, (long long)T * T, inv_scale);

    // out_pre = scores @ v (K limited to bm+BM); longest-K blocks first (LPT)
    gemm_bt<OP_NONE, true, false, true><<<dim3(T / BM, C / BN, NB), blk, 0, stream>>>(
        scb, vT, opre, nullptr, nullptr, nullptr, T, C, T,
        (long long)T * T, (long long)T * C, (long long)T * C, 1.f);

    layernorm_h<<<dim3(MT, 1, 1), dim3(256, 1, 1), 0, stream>>>(
        opre, lnw, lnb, (float*)d_out);
}

// Round 9
// 533.975 us; speedup vs baseline: 1.2885x; 1.1099x over previous
//
#include <hip/hip_runtime.h>
#include <math.h>

#define BM 128
#define BN 128
#define BK 64

typedef _Float16 f16x8 __attribute__((ext_vector_type(8)));
typedef __attribute__((ext_vector_type(4))) float f32x4;

typedef const __attribute__((address_space(1))) void* gas_ptr;
typedef __attribute__((address_space(3))) void* las_ptr;

enum { OP_NONE = 0, OP_BIAS_GELU = 1, OP_BIAS = 2, OP_SCALE_MASK = 3 };

__device__ __forceinline__ unsigned short f2h(float f) {
    _Float16 h = (_Float16)f;  // RTNE
    unsigned short u;
    __builtin_memcpy(&u, &h, 2);
    return u;
}
__device__ __forceinline__ float h2f(unsigned short u) {
    _Float16 h;
    __builtin_memcpy(&h, &u, 2);
    return (float)h;
}

// tanh-form GELU via sigmoid: ~7 VALU instrs vs ~50 for libm erff.
// R6/R7 confirmed: absmax stays 0.03125 with this approximation.
__device__ __forceinline__ float fast_gelu(float x) {
    float x2 = x * x;
    float p  = x * (-1.5957691216f - 0.0713548164f * x2);  // = -2u
    float t  = __expf(p);                                  // e^{-2u}
    return x * __builtin_amdgcn_rcpf(1.0f + t);            // x * sigma(2u)
}

// C = A @ B, B given transposed (BT is [N][K] row-major). A [M][K], C [M][N].
// fp16 in/out, fp32 accumulate. BK=64 XOR-swizzled global_load_lds staging
// (0 bank conflicts, R4). M-fastest grid -> same-XCD A-stripe reuse (R5).
// Direct scatter epilogue (R6's LDS repack regressed; R7 reverted).
// __launch_bounds__(256, 4): R8 ran 3 blocks/CU (84 VGPR + 64 AGPR = 148/wave
// -> floor(512/148)=3); capping at 128 total regs buys a 4th resident block
// per CU to fill the ~39% barrier-idle window (m114 co-scheduling).
template <int EPI, bool CAUSAL_K, bool TRI, bool REVM>
__global__ __launch_bounds__(256, 4) void gemm_bt(
    const unsigned short* __restrict__ A,
    const unsigned short* __restrict__ BT,
    unsigned short* __restrict__ Cw,
    const float* __restrict__ bias0,
    const float* __restrict__ bias1,
    const float* __restrict__ bias2,
    int M, int N, int K,
    long long sA, long long sB, long long sC,
    float scale)
{
    __shared__ __align__(16) unsigned short As[BM * BK];
    __shared__ __align__(16) unsigned short Bs[BN * BK];

    const int tid  = threadIdx.x;
    const int wave = tid >> 6;
    const int lane = tid & 63;

    int bm, bn, z;
    if (TRI) {
        // unrank t -> (i, j), j <= i, t = i(i+1)/2 + j
        const int t = blockIdx.x;
        int i = (int)((sqrtf(8.0f * t + 1.0f) - 1.0f) * 0.5f);
        while ((i + 1) * (i + 2) / 2 <= t) i++;
        while (i * (i + 1) / 2 > t) i--;
        const int j = t - i * (i + 1) / 2;
        bm = i * BM;
        bn = j * BN;
        z  = blockIdx.y;
    } else {
        bm = (REVM ? (gridDim.x - 1 - blockIdx.x) : blockIdx.x) * BM;
        bn = blockIdx.y * BN;
        z  = blockIdx.z;
    }

    const unsigned short* Ab = A  + (long long)z * sA;
    const unsigned short* Bb = BT + (long long)z * sB;
    unsigned short*       Cb = Cw + (long long)z * sC;
    const float* bias = nullptr;
    if (EPI == OP_BIAS || EPI == OP_BIAS_GELU)
        bias = (z == 0) ? bias0 : (z == 1) ? bias1 : bias2;

    const int wm = (wave >> 1) * 64;  // wave's 64x64 quadrant
    const int wn = (wave & 1) * 64;

    f32x4 acc[4][4];
    #pragma unroll
    for (int i = 0; i < 4; i++)
        #pragma unroll
        for (int j = 0; j < 4; j++)
            acc[i][j] = (f32x4){0.f, 0.f, 0.f, 0.f};

    int Keff = K;
    if (CAUSAL_K) {
        int kl = bm + BM;
        Keff = kl < K ? kl : K;
    }

    const int srow = lane >> 3;                          // row within 8-row slab
    const int gchw = ((lane & 7) ^ (srow & 7)) * 8;      // swizzled chunk, halfwords
    const int fr   = lane & 15;
    const int quad = lane >> 4;

    // per-lane global staging pointers; advance by BK per iter
    const unsigned short* pA = Ab + (long long)(bm + wave * 32 + srow) * K + gchw;
    const unsigned short* pB = Bb + (long long)(bn + wave * 32 + srow) * K + gchw;
    const long long rstep = 8ll * K;  // 8 rows between the 4 slabs of a wave

    for (int k0 = 0; k0 < Keff; k0 += BK) {
        #pragma unroll
        for (int s = 0; s < 4; ++s) {
            const int t = wave * 4 + s;
            __builtin_amdgcn_global_load_lds((gas_ptr)(const void*)(pA + s * rstep),
                                             (las_ptr)(void*)&As[t * 512 + lane * 8],
                                             16, 0, 0);
            __builtin_amdgcn_global_load_lds((gas_ptr)(const void*)(pB + s * rstep),
                                             (las_ptr)(void*)&Bs[t * 512 + lane * 8],
                                             16, 0, 0);
        }
        pA += BK;
        pB += BK;
        __syncthreads();  // drains vmcnt -> staged data visible

        #pragma unroll
        for (int kk = 0; kk < 2; ++kk) {
            f16x8 fa[4], fb[4];
            #pragma unroll
            for (int i = 0; i < 4; i++) {
                const int row  = wm + i * 16 + fr;
                const int slot = row * 8 + ((kk * 4 + quad) ^ (fr & 7));
                fa[i] = *(const f16x8*)&As[slot * 8];
            }
            #pragma unroll
            for (int j = 0; j < 4; j++) {
                const int row  = wn + j * 16 + fr;
                const int slot = row * 8 + ((kk * 4 + quad) ^ (fr & 7));
                fb[j] = *(const f16x8*)&Bs[slot * 8];
            }
            #pragma unroll
            for (int i = 0; i < 4; i++)
                #pragma unroll
                for (int j = 0; j < 4; j++)
                    acc[i][j] = __builtin_amdgcn_mfma_f32_16x16x32_f16(
                        fa[i], fb[j], acc[i][j], 0, 0, 0);
        }
        __syncthreads();  // protect LDS before next stage overwrites
    }

    // epilogue: C/D layout col=lane&15, row=(lane>>4)*4+reg  [m89/m91]
    const int er = quad;
    const int ec = fr;
    #pragma unroll
    for (int j = 0; j < 4; j++) {
        const int col = bn + wn + j * 16 + ec;
        float bj = 0.f;
        if (EPI == OP_BIAS || EPI == OP_BIAS_GELU) bj = bias[col];
        #pragma unroll
        for (int i = 0; i < 4; i++) {
            #pragma unroll
            for (int r = 0; r < 4; r++) {
                const int row = bm + wm + i * 16 + er * 4 + r;
                float v = acc[i][j][r];
                if (EPI == OP_BIAS_GELU) {
                    v = fast_gelu(v + bj);
                } else if (EPI == OP_BIAS) {
                    v += bj;
                } else if (EPI == OP_SCALE_MASK) {
                    v *= scale;
                    if (col > row) v = 0.f;
                }
                Cb[(long long)row * N + col] = f2h(v);
            }
        }
    }
}

// fp32 -> fp16 elementwise (n divisible by 1024)
__global__ __launch_bounds__(256) void cvt_f32_f16(
    const float4* __restrict__ in, ushort4* __restrict__ out)
{
    int i = blockIdx.x * 256 + threadIdx.x;
    float4 f = in[i];
    ushort4 o;
    o.x = f2h(f.x); o.y = f2h(f.y); o.z = f2h(f.z); o.w = f2h(f.w);
    out[i] = o;
}

// all six weight matrices: fp32 -> fp16 transposed, one dispatch (z=0..5).
__global__ __launch_bounds__(256) void wprep(
    const float* __restrict__ s0, const float* __restrict__ s1,
    const float* __restrict__ s2, const float* __restrict__ s3,
    const float* __restrict__ s4, const float* __restrict__ s5,
    unsigned short* __restrict__ W1T, unsigned short* __restrict__ W2T)
{
    const int C = 1024;
    const int z = blockIdx.z;
    const float* in = (z == 0) ? s0 : (z == 1) ? s1 : (z == 2) ? s2
                    : (z == 3) ? s3 : (z == 4) ? s4 : s5;
    unsigned short* out = (z < 3) ? (W1T + (long long)z * C * C)
                                  : (W2T + (long long)(z - 3) * C * C);
    __shared__ unsigned short tile[32][33];
    const int bx = blockIdx.x * 32;  // col base
    const int by = blockIdx.y * 32;  // row base
    const int x = threadIdx.x;
    for (int y = threadIdx.y; y < 32; y += 8)
        tile[y][x] = f2h(in[(long long)(by + y) * C + (bx + x)]);
    __syncthreads();
    for (int y = threadIdx.y; y < 32; y += 8)
        out[(long long)(bx + y) * C + (by + x)] = tile[x][y];
}

// wide fp16 transpose: 64x64 tiles, ushort4 (8B) loads AND stores.
// grid (cols/64, rows/64, NB); out[col][row] = in[row][col].
__global__ __launch_bounds__(256) void transpose64_f16(
    const unsigned short* __restrict__ in,
    unsigned short* __restrict__ out,
    int rows, int cols,
    long long sIn, long long sOut)
{
    __shared__ unsigned short tile[64][68];  // stride 68 shorts = 136 B (8B-aligned)
    const unsigned short* ip = in  + (long long)blockIdx.z * sIn;
    unsigned short*       op = out + (long long)blockIdx.z * sOut;
    const int bx = blockIdx.x * 64;  // col base
    const int by = blockIdx.y * 64;  // row base
    const int tid = threadIdx.x;
    const int rsub = tid >> 4;        // 0..15
    const int c4   = (tid & 15) * 4;  // 0,4,..,60
    #pragma unroll
    for (int it = 0; it < 4; it++) {
        const int r = it * 16 + rsub;
        ushort4 v = *(const ushort4*)&ip[(long long)(by + r) * cols + (bx + c4)];
        tile[r][c4]     = v.x;
        tile[r][c4 + 1] = v.y;
        tile[r][c4 + 2] = v.z;
        tile[r][c4 + 3] = v.w;
    }
    __syncthreads();
    #pragma unroll
    for (int it = 0; it < 4; it++) {
        const int cc = it * 16 + rsub;  // out row = in col
        ushort4 v;
        v.x = tile[c4][cc];
        v.y = tile[c4 + 1][cc];
        v.z = tile[c4 + 2][cc];
        v.w = tile[c4 + 3][cc];
        *(ushort4*)&op[(long long)(bx + cc) * rows + (by + c4)] = v;
    }
}

// one 256-thread block per row of 1024; fp16 in, fp32 params, fp32 out
__global__ __launch_bounds__(256) void layernorm_h(
    const unsigned short* __restrict__ X,
    const float* __restrict__ W,
    const float* __restrict__ Bv,
    float* __restrict__ Y)
{
    const int row = blockIdx.x;
    const int tid = threadIdx.x;
    ushort4 u = ((const ushort4*)(X + (long long)row * 1024))[tid];
    float f0 = h2f(u.x), f1 = h2f(u.y), f2 = h2f(u.z), f3 = h2f(u.w);
    float s  = f0 + f1 + f2 + f3;
    float ss = f0 * f0 + f1 * f1 + f2 * f2 + f3 * f3;
    #pragma unroll
    for (int off = 32; off > 0; off >>= 1) {
        s  += __shfl_down(s, off);
        ss += __shfl_down(ss, off);
    }
    __shared__ float red[2][4];
    const int wv = tid >> 6;
    if ((tid & 63) == 0) { red[0][wv] = s; red[1][wv] = ss; }
    __syncthreads();
    float S  = red[0][0] + red[0][1] + red[0][2] + red[0][3];
    float SS = red[1][0] + red[1][1] + red[1][2] + red[1][3];
    float mu  = S * (1.f / 1024.f);
    float var = SS * (1.f / 1024.f) - mu * mu;
    float rs  = rsqrtf(var + 1e-5f);
    float4 w4 = ((const float4*)W)[tid];
    float4 b4 = ((const float4*)Bv)[tid];
    float4 o;
    o.x = (f0 - mu) * rs * w4.x + b4.x;
    o.y = (f1 - mu) * rs * w4.y + b4.y;
    o.z = (f2 - mu) * rs * w4.z + b4.z;
    o.w = (f3 - mu) * rs * w4.w + b4.w;
    ((float4*)(Y + (long long)row * 1024))[tid] = o;
}

extern "C" void kernel_launch(void* const* d_in, const int* in_sizes, int n_in,
                              void* d_out, int out_size, void* d_ws, size_t ws_size,
                              hipStream_t stream)
{
    const int C  = 1024;
    const int T  = 2048;
    const int NB = 8;
    const int MT = NB * T;  // 16384 rows

    const float* x = (const float*)d_in[0];
    const float* W1q = (const float*)d_in[1];
    const float* b1q = (const float*)d_in[2];
    const float* W2q = (const float*)d_in[3];
    const float* b2q = (const float*)d_in[4];
    const float* W1k = (const float*)d_in[5];
    const float* b1k = (const float*)d_in[6];
    const float* W2k = (const float*)d_in[7];
    const float* b2k = (const float*)d_in[8];
    const float* W1v = (const float*)d_in[9];
    const float* b1v = (const float*)d_in[10];
    const float* W2v = (const float*)d_in[11];
    const float* b2v = (const float*)d_in[12];
    const float* lnw = (const float*)d_in[13];
    const float* lnb = (const float*)d_in[14];

    char* wsp = (char*)d_ws;
    auto take = [&](size_t bytes) {
        char* p = wsp;
        wsp += (bytes + 255) & ~(size_t)255;
        return p;
    };

    const size_t MATE = (size_t)MT * C;  // elements per [16384][1024] matrix

    unsigned short* W1T  = (unsigned short*)take((size_t)3 * C * C * 2);
    unsigned short* W2T  = (unsigned short*)take((size_t)3 * C * C * 2);
    unsigned short* xb   = (unsigned short*)take(MATE * 2);
    unsigned short* qkv  = (unsigned short*)take(3 * MATE * 2);  // q,k,v contiguous
    unsigned short* hreg = (unsigned short*)take(3 * MATE * 2);  // h; later scb+opre
    unsigned short* qb   = qkv;
    unsigned short* kb   = qkv + MATE;
    unsigned short* vb   = qkv + 2 * MATE;
    unsigned short* vT   = xb;                               // xb dead after MLP1
    unsigned short* scb  = hreg;                             // 8*T*T = 2*MATE elems
    unsigned short* opre = hreg + (size_t)NB * T * T;        // MATE elems — exact fit

    // x: fp32 -> fp16
    cvt_f32_f16<<<dim3(MT * C / 1024, 1, 1), dim3(256, 1, 1), 0, stream>>>(
        (const float4*)x, (ushort4*)xb);

    // all weights: fp32 -> fp16 transposed, one dispatch
    wprep<<<dim3(C / 32, C / 32, 6), dim3(32, 8, 1), 0, stream>>>(
        W1q, W1k, W1v, W2q, W2k, W2v, W1T, W2T);

    dim3 blk(256, 1, 1);

    // MLP GEMM1 (z = head): h_z = GELU(x @ W1_z + b1_z)   grid (M,N,z)
    gemm_bt<OP_BIAS_GELU, false, false, false><<<dim3(MT / BM, C / BN, 3), blk, 0, stream>>>(
        xb, W1T, hreg, b1q, b1k, b1v, MT, C, C,
        0, (long long)C * C, (long long)MATE, 1.f);

    // MLP GEMM2 (z = head): {q,k,v}_z = h_z @ W2_z + b2_z
    gemm_bt<OP_BIAS, false, false, false><<<dim3(MT / BM, C / BN, 3), blk, 0, stream>>>(
        hreg, W2T, qkv, b2q, b2k, b2v, MT, C, C,
        (long long)MATE, (long long)C * C, (long long)MATE, 1.f);

    // vT[b] = v[b]^T ([C][T] per batch) for the scores@v GEMM's BT operand
    transpose64_f16<<<dim3(C / 64, T / 64, NB), blk, 0, stream>>>(
        vb, vT, T, C, (long long)T * C, (long long)T * C);

    // scores = tril(q @ k^T) / sqrt(C*T); packed lower-triangle grid
    float inv_scale = 1.0f / sqrtf((float)C * (float)T);
    gemm_bt<OP_SCALE_MASK, false, true, false><<<dim3(136, NB, 1), blk, 0, stream>>>(
        qb, kb, scb, nullptr, nullptr, nullptr, T, T, C,
        (long long)T * C, (long long)T * C, (long long)T * T, inv_scale);

    // out_pre = scores @ v (K limited to bm+BM); longest-K blocks first (LPT)
    gemm_bt<OP_NONE, true, false, true><<<dim3(T / BM, C / BN, NB), blk, 0, stream>>>(
        scb, vT, opre, nullptr, nullptr, nullptr, T, C, T,
        (long long)T * T, (long long)T * C, (long long)T * C, 1.f);

    layernorm_h<<<dim3(MT, 1, 1), dim3(256, 1, 1), 0, stream>>>(
        opre, lnw, lnb, (float*)d_out);
}